// Round 1
// baseline (511.274 us; speedup 1.0000x reference)
//
#include <hip/hip_runtime.h>
#include <cstddef>

// Problem constants
#define BATCH   8
#define SEQ     1024
#define DMODEL  1024
#define NHEAD   16
#define HDIM    64
#define D3      3072
#define NROWS   (BATCH * SEQ)   // 8192
#define LN_EPS  1e-5f

typedef __attribute__((ext_vector_type(4))) float f32x4;
typedef __attribute__((ext_vector_type(8))) short bf16x8;

// ---------- bf16 helpers ----------
__device__ __forceinline__ float b2f(unsigned short u) {
    union { unsigned int i; float f; } v; v.i = ((unsigned int)u) << 16; return v.f;
}
__device__ __forceinline__ unsigned short f2bu(float f) {  // round-to-nearest-even
    union { float f; unsigned int i; } v; v.f = f;
    unsigned int r = v.i + 0x7fffu + ((v.i >> 16) & 1u);
    return (unsigned short)(r >> 16);
}
// async global->LDS, 16B per lane (wave-uniform base + lane*16)
__device__ __forceinline__ void gl16(const void* g, void* l) {
    __builtin_amdgcn_global_load_lds(
        (const __attribute__((address_space(1))) unsigned int*)g,
        (__attribute__((address_space(3))) unsigned int*)l, 16, 0, 0);
}

// =====================================================================
// K0: fp32 -> bf16 conversion of x, in_proj_w, out_proj_w
// =====================================================================
#define NG_X  1048576   // 8192*1024/8
#define NG_WQ 393216    // 3072*1024/8
#define NG_WO 131072    // 1024*1024/8
__global__ __launch_bounds__(256)
void cvt_bf16(const float* __restrict__ x, const float* __restrict__ wq,
              const float* __restrict__ wo,
              unsigned short* __restrict__ xb, unsigned short* __restrict__ wqb,
              unsigned short* __restrict__ wob) {
    const int gidx = blockIdx.x * 256 + threadIdx.x;
    const float* src; unsigned short* dst; size_t off;
    if (gidx < NG_X)              { src = x;  dst = xb;  off = (size_t)gidx * 8; }
    else if (gidx < NG_X + NG_WQ) { src = wq; dst = wqb; off = (size_t)(gidx - NG_X) * 8; }
    else                          { src = wo; dst = wob; off = (size_t)(gidx - NG_X - NG_WQ) * 8; }
    float4 v0 = *(const float4*)(src + off);
    float4 v1 = *(const float4*)(src + off + 4);
    uint4 pv;
    pv.x = f2bu(v0.x) | ((unsigned int)f2bu(v0.y) << 16);
    pv.y = f2bu(v0.z) | ((unsigned int)f2bu(v0.w) << 16);
    pv.z = f2bu(v1.x) | ((unsigned int)f2bu(v1.y) << 16);
    pv.w = f2bu(v1.z) | ((unsigned int)f2bu(v1.w) << 16);
    *(uint4*)(dst + off) = pv;
}

// =====================================================================
// K1: qkv MFMA GEMM. C[8192,3072] = xb @ wb^T + bias  (bf16 in, bf16 out)
// Q -> qh[(b*16+h)][tok][64], K -> kh[(b*16+h)][key][64]  (per-head slabs)
// V -> vt[(b*16+h)*64+d][key] transposed.
// 128x128 tile, BK=32, 4 waves (2x2), 16x16x32 MFMA, global_load_lds x16B.
// =====================================================================
__global__ __launch_bounds__(256)
void qkv_mfma(const unsigned short* __restrict__ xb,    // [8192][1024]
              const unsigned short* __restrict__ wb,    // [3072][1024]
              const float* __restrict__ bias,           // [3072]
              unsigned short* __restrict__ qh,          // [128][1024][64]
              unsigned short* __restrict__ kh,          // [128][1024][64]
              unsigned short* __restrict__ vt) {        // [128*64][1024]
    __shared__ unsigned short smem[8192];               // As 4096 | Bs 4096 (16 KB)
    unsigned short* As = smem;
    unsigned short* Bs = smem + 4096;

    const int t = threadIdx.x;
    const int w = t >> 6, lane = t & 63;
    const int wm = w >> 1, wn = w & 1;
    const int g = lane >> 4, c = lane & 15;
    const int m0 = blockIdx.y * 128, n0 = blockIdx.x * 128;

    const int srow = t >> 2;            // 0..63
    const int scol = (t & 3) * 8;       // 0,8,16,24
    const unsigned short* ga = xb + (size_t)(m0 + srow) * 1024 + scol;
    const unsigned short* gb = wb + (size_t)(n0 + srow) * 1024 + scol;

    f32x4 acc[4][4];
#pragma unroll
    for (int i = 0; i < 4; ++i)
#pragma unroll
        for (int j = 0; j < 4; ++j) acc[i][j] = (f32x4){0.f, 0.f, 0.f, 0.f};

    for (int k0 = 0; k0 < 1024; k0 += 32) {
        gl16(ga + k0,             As + t * 8);
        gl16(ga + 64 * 1024 + k0, As + 2048 + t * 8);
        gl16(gb + k0,             Bs + t * 8);
        gl16(gb + 64 * 1024 + k0, Bs + 2048 + t * 8);
        __syncthreads();                         // drains vmcnt -> tile visible
        bf16x8 af[4], bf[4];
#pragma unroll
        for (int i = 0; i < 4; ++i)
            af[i] = *(const bf16x8*)(As + (wm * 64 + i * 16 + c) * 32 + g * 8);
#pragma unroll
        for (int j = 0; j < 4; ++j)
            bf[j] = *(const bf16x8*)(Bs + (wn * 64 + j * 16 + c) * 32 + g * 8);
#pragma unroll
        for (int i = 0; i < 4; ++i)
#pragma unroll
            for (int j = 0; j < 4; ++j)
                acc[i][j] = __builtin_amdgcn_mfma_f32_16x16x32_bf16(af[i], bf[j], acc[i][j], 0, 0, 0);
        __syncthreads();                         // protect tile before next overwrite
    }

    float bsv[4];
#pragma unroll
    for (int j = 0; j < 4; ++j) bsv[j] = bias[n0 + wn * 64 + j * 16 + c];

    unsigned short* eslice = smem + w * 2048;    // 4 KB per-wave epilogue slice
    const int b_ = m0 >> 10;                     // batch (tile never straddles)

    if (n0 < 2048) {
        // ---- Q or K: per-head slab [128 slabs][1024 tok][64 d] ----
        const int ncl   = n0 + wn * 64;          // wave's 64-col slice = one head
        unsigned short* dst = (ncl < 1024)
            ? qh + ((size_t)(b_ * 16 + (ncl >> 6)) * 1024) * 64
            : kh + ((size_t)(b_ * 16 + ((ncl - 1024) >> 6)) * 1024) * 64;
#pragma unroll
        for (int half = 0; half < 2; ++half) {
#pragma unroll
            for (int ii = 0; ii < 2; ++ii) {
                const int i = half * 2 + ii;
#pragma unroll
                for (int j = 0; j < 4; ++j)
#pragma unroll
                    for (int r = 0; r < 4; ++r)
                        eslice[(ii * 16 + g * 4 + r) * 64 + j * 16 + c] = f2bu(acc[i][j][r] + bsv[j]);
            }
#pragma unroll
            for (int u = 0; u < 4; ++u) {
                const int mloc = u * 8 + (lane >> 3);       // 0..31
                const int ncol = (lane & 7) * 8;
                bf16x8 row = *(const bf16x8*)(eslice + mloc * 64 + ncol);
                const int tok = (m0 & 1023) + wm * 64 + half * 32 + mloc;
                *(bf16x8*)(dst + (size_t)tok * 64 + ncol) = row;
            }
        }
    } else {
        // ---- V: transposed into vt[(b*16+h)*64+d][key], XOR-swizzled LDS ----
        const int key0  = (m0 & 1023) + wm * 64;
        const int hbase = (n0 + wn * 64 - 2048) >> 6;
#pragma unroll
        for (int half = 0; half < 2; ++half) {
#pragma unroll
            for (int jj = 0; jj < 2; ++jj) {
                const int j = half * 2 + jj;
                const int nloc = jj * 16 + c;               // 0..31
#pragma unroll
                for (int i = 0; i < 4; ++i)
#pragma unroll
                    for (int r = 0; r < 4; ++r) {
                        const int mloc  = i * 16 + g * 4 + r;
                        const int mphys = mloc ^ ((nloc & 7) << 3);
                        eslice[nloc * 64 + mphys] = f2bu(acc[i][j][r] + bsv[j]);
                    }
            }
#pragma unroll
            for (int u = 0; u < 4; ++u) {
                const int nloc  = u * 8 + (lane >> 3);      // 0..31
                const int mb    = lane & 7;
                const int mphys = (mb ^ (nloc & 7)) * 8;
                bf16x8 row = *(const bf16x8*)(eslice + nloc * 64 + mphys);
                const int d = half * 32 + nloc;
                *(bf16x8*)(vt + ((size_t)((b_ * 16 + hbase) * 64 + d)) * 1024 + key0 + mb * 8) = row;
            }
        }
    }
}

// =====================================================================
// K2: MFMA attention. Block = (qtile of 16 rows, batch, head-group of 8).
// 256 threads, 4 waves splitting the key dimension (256 keys each).
// Occupancy redesign vs prior version:
//  - QK^T is chunked: e-values go straight to LDS (unnormalized bf16),
//    freeing the 64-VGPR acc[16] that used to live across the barrier.
//  - PV runs on unnormalized e; O is scaled by 1/L at the store.
//  - wsum re-reads its OWN bf16 e-values from P_s (err ~2^-9 << tol).
//  - 2 barriers/head instead of 3.
//  - Heads split 2 ways across blockIdx.z -> grid 1024; wout is summed
//    via atomicAdd into a pre-zeroed buffer (2 contenders/element).
// Target: <=128 VGPR -> 4 waves/SIMD; LDS 33.3KB -> 4 blocks/CU.
// =====================================================================
__global__ __launch_bounds__(256, 4)
void attn_mfma(const unsigned short* __restrict__ qh,   // [128][1024][64]
               const unsigned short* __restrict__ kh,   // [128][1024][64]
               const unsigned short* __restrict__ vt,   // [128][64][1024]
               const float* __restrict__ tdp,
               unsigned short* __restrict__ attnb,       // [8192][1024] bf16
               float* __restrict__ wout) {               // [8192][1024] pre-zeroed
    const int qt = blockIdx.x;      // 0..63
    const int b  = blockIdx.y;      // 0..7
    const int hg = blockIdx.z;      // 0..1 (head group)
    const int t  = threadIdx.x;
    const int w  = t >> 6;          // wave 0..3
    const int lane = t & 63;
    const int g  = lane >> 4;       // quad group 0..3
    const int c  = lane & 15;

    const int q0 = qt * 16;
    const float td = -fabsf(tdp[0]);

    __shared__ unsigned short P_s[16][1032];   // unnormalized e (bf16)
    __shared__ float rs_s[4][16];              // per-wave row sums

    float wsum[16][4];                          // head-mean accumulator (C layout)
#pragma unroll
    for (int tt = 0; tt < 16; ++tt)
#pragma unroll
        for (int r = 0; r < 4; ++r) wsum[tt][r] = 0.f;

    const int key_base = w * 256;               // wave's key range in QK^T

    for (int hi = 0; hi < 8; ++hi) {
        const int h = hg * 8 + hi;
        const unsigned short* qslab = qh + (size_t)(b * 16 + h) * 1024 * 64;
        const unsigned short* kslab = kh + (size_t)(b * 16 + h) * 1024 * 64;

        // A-frags: Q rows within the head slab (2KB window per frag)
        bf16x8 qa0 = *(const bf16x8*)(qslab + (size_t)(q0 + c) * 64 + g * 8);
        bf16x8 qa1 = *(const bf16x8*)(qslab + (size_t)(q0 + c) * 64 + 32 + g * 8);

        // ---- chunked QK^T: compute e, dump to LDS, keep only rsum ----
        float rsum[4] = {0.f, 0.f, 0.f, 0.f};
#pragma unroll 2
        for (int tt = 0; tt < 16; ++tt) {
            const int key = key_base + tt * 16 + c;      // B-frag n = c
            const unsigned short* kp = kslab + (size_t)key * 64 + g * 8;
            bf16x8 kb0 = *(const bf16x8*)(kp);
            bf16x8 kb1 = *(const bf16x8*)(kp + 32);
            f32x4 z = {0.f, 0.f, 0.f, 0.f};
            z = __builtin_amdgcn_mfma_f32_16x16x32_bf16(qa0, kb0, z, 0, 0, 0);
            z = __builtin_amdgcn_mfma_f32_16x16x32_bf16(qa1, kb1, z, 0, 0, 0);
            const float kf = (float)key;
#pragma unroll
            for (int r = 0; r < 4; ++r) {
                const float qf = (float)(q0 + g * 4 + r);
                const float e = __expf(z[r] * 0.125f + td * fabsf(kf - qf));
                rsum[r] += e;
                P_s[g * 4 + r][key_base + tt * 16 + c] = f2bu(e);
            }
        }
#pragma unroll
        for (int r = 0; r < 4; ++r) {
            rsum[r] += __shfl_xor(rsum[r], 1, 64);
            rsum[r] += __shfl_xor(rsum[r], 2, 64);
            rsum[r] += __shfl_xor(rsum[r], 4, 64);
            rsum[r] += __shfl_xor(rsum[r], 8, 64);
        }
        if (c == 0) {
#pragma unroll
            for (int r = 0; r < 4; ++r) rs_s[w][g * 4 + r] = rsum[r];
        }
        __syncthreads();                        // publishes P_s AND rs_s

        float invl[4];
#pragma unroll
        for (int r = 0; r < 4; ++r) {
            const int row = g * 4 + r;
            invl[r] = 1.0f / (rs_s[0][row] + rs_s[1][row] + rs_s[2][row] + rs_s[3][row]);
        }

        // ---- PV on unnormalized e; scale O by 1/L at the store ----
        f32x4 accO = {0.f, 0.f, 0.f, 0.f};
        const unsigned short* vhp = vt + (size_t)((b * 16 + h) * 64 + w * 16 + c) * 1024;
#pragma unroll 8
        for (int ks = 0; ks < 32; ++ks) {
            bf16x8 pa = *(const bf16x8*)(&P_s[c][ks * 32 + g * 8]);
            bf16x8 vb = *(const bf16x8*)(vhp + ks * 32 + g * 8);
            accO = __builtin_amdgcn_mfma_f32_16x16x32_bf16(pa, vb, accO, 0, 0, 0);
        }
        unsigned short* op = attnb + (size_t)(b * 1024 + q0) * 1024 + h * 64 + w * 16 + c;
#pragma unroll
        for (int r = 0; r < 4; ++r)
            op[(size_t)(g * 4 + r) * 1024] = f2bu(accO[r] * invl[r]);

        // ---- wsum: re-read own e-values (bf16) and normalize ----
#pragma unroll
        for (int tt = 0; tt < 16; ++tt)
#pragma unroll
            for (int r = 0; r < 4; ++r)
                wsum[tt][r] += b2f(P_s[g * 4 + r][key_base + tt * 16 + c]) * invl[r];
        __syncthreads();                        // P_s reusable next head
    }

    // head-group partial -> atomic accumulate (2 contenders per element)
#pragma unroll
    for (int tt = 0; tt < 16; ++tt) {
#pragma unroll
        for (int r = 0; r < 4; ++r) {
            atomicAdd(&wout[(size_t)(b * 1024 + q0 + g * 4 + r) * 1024 + key_base + tt * 16 + c],
                      wsum[tt][r] * (1.0f / NHEAD));
        }
    }
}

// =====================================================================
// K3: outproj MFMA. y = attnb @ wob^T + bias + x   (bf16 in, fp32 out)
// =====================================================================
__global__ __launch_bounds__(256)
void outproj_mfma(const unsigned short* __restrict__ ab,   // [8192][1024]
                  const unsigned short* __restrict__ wob,  // [1024][1024]
                  const float* __restrict__ bias,
                  const float* __restrict__ X,
                  float* __restrict__ Y) {
    __shared__ unsigned short smem[8192];
    unsigned short* As = smem;
    unsigned short* Bs = smem + 4096;

    const int t = threadIdx.x;
    const int w = t >> 6, lane = t & 63;
    const int wm = w >> 1, wn = w & 1;
    const int g = lane >> 4, c = lane & 15;
    const int m0 = blockIdx.y * 128, n0 = blockIdx.x * 128;

    const int srow = t >> 2;
    const int scol = (t & 3) * 8;
    const unsigned short* ga = ab  + (size_t)(m0 + srow) * 1024 + scol;
    const unsigned short* gb = wob + (size_t)(n0 + srow) * 1024 + scol;

    f32x4 acc[4][4];
#pragma unroll
    for (int i = 0; i < 4; ++i)
#pragma unroll
        for (int j = 0; j < 4; ++j) acc[i][j] = (f32x4){0.f, 0.f, 0.f, 0.f};

    for (int k0 = 0; k0 < 1024; k0 += 32) {
        gl16(ga + k0,             As + t * 8);
        gl16(ga + 64 * 1024 + k0, As + 2048 + t * 8);
        gl16(gb + k0,             Bs + t * 8);
        gl16(gb + 64 * 1024 + k0, Bs + 2048 + t * 8);
        __syncthreads();
        bf16x8 af[4], bf[4];
#pragma unroll
        for (int i = 0; i < 4; ++i)
            af[i] = *(const bf16x8*)(As + (wm * 64 + i * 16 + c) * 32 + g * 8);
#pragma unroll
        for (int j = 0; j < 4; ++j)
            bf[j] = *(const bf16x8*)(Bs + (wn * 64 + j * 16 + c) * 32 + g * 8);
#pragma unroll
        for (int i = 0; i < 4; ++i)
#pragma unroll
            for (int j = 0; j < 4; ++j)
                acc[i][j] = __builtin_amdgcn_mfma_f32_16x16x32_bf16(af[i], bf[j], acc[i][j], 0, 0, 0);
        __syncthreads();
    }

    float bsv[4];
#pragma unroll
    for (int j = 0; j < 4; ++j) bsv[j] = bias[n0 + wn * 64 + j * 16 + c];

#pragma unroll
    for (int i = 0; i < 4; ++i) {
#pragma unroll
        for (int r = 0; r < 4; ++r) {
            const int m = m0 + wm * 64 + i * 16 + g * 4 + r;
#pragma unroll
            for (int j = 0; j < 4; ++j) {
                const int n = n0 + wn * 64 + j * 16 + c;
                Y[(size_t)m * 1024 + n] = acc[i][j][r] + bsv[j] + X[(size_t)m * 1024 + n];
            }
        }
    }
}

// =====================================================================
// K4: LayerNorm per row -> final out
// =====================================================================
__global__ __launch_bounds__(256)
void ln_kernel(const float* __restrict__ Y, const float* __restrict__ lnw,
               const float* __restrict__ lnb, float* __restrict__ out) {
    const int row = blockIdx.x, t = threadIdx.x;
    __shared__ float rs[256], rq[256];
    const float4 v = ((const float4*)(Y + (size_t)row * DMODEL))[t];
    rs[t] = v.x + v.y + v.z + v.w;
    rq[t] = v.x * v.x + v.y * v.y + v.z * v.z + v.w * v.w;
    __syncthreads();
    for (int off = 128; off > 0; off >>= 1) {
        if (t < off) { rs[t] += rs[t + off]; rq[t] += rq[t + off]; }
        __syncthreads();
    }
    const float mu   = rs[0] * (1.0f / DMODEL);
    const float var  = rq[0] * (1.0f / DMODEL) - mu * mu;
    const float rstd = rsqrtf(var + LN_EPS);
    const float4 w  = ((const float4*)lnw)[t];
    const float4 bb = ((const float4*)lnb)[t];
    float4 o;
    o.x = (v.x - mu) * rstd * w.x + bb.x;
    o.y = (v.y - mu) * rstd * w.y + bb.y;
    o.z = (v.z - mu) * rstd * w.z + bb.z;
    o.w = (v.w - mu) * rstd * w.w + bb.w;
    ((float4*)(out + (size_t)row * DMODEL))[t] = o;
}

// =====================================================================
extern "C" void kernel_launch(void* const* d_in, const int* in_sizes, int n_in,
                              void* d_out, int out_size, void* d_ws, size_t ws_size,
                              hipStream_t stream) {
    (void)in_sizes; (void)n_in; (void)out_size; (void)ws_size;
    const float* x    = (const float*)d_in[0];
    const float* td   = (const float*)d_in[1];
    const float* wqkv = (const float*)d_in[2];
    const float* bqkv = (const float*)d_in[3];
    const float* wo   = (const float*)d_in[4];
    const float* bo   = (const float*)d_in[5];
    const float* lnw  = (const float*)d_in[6];
    const float* lnb  = (const float*)d_in[7];

    float* out_ln = (float*)d_out;                         // final out [8192,1024]
    float* out_w  = (float*)d_out + (size_t)NROWS * SEQ;   // mean weights [8,1024,1024]

    // ws (peak 48 MiB):
    //   qh bf16 [128][1024][64] @0        (16 MiB)
    //   kh bf16 [128][1024][64] @+16 MiB  (16 MiB)
    //   vt bf16 [128*64][1024]  @+32 MiB  (16 MiB)
    //   y  fp32 [8192][1024] reuses offset 0 after attn (qh/kh dead).
    unsigned short* qh = (unsigned short*)d_ws;
    unsigned short* kh = qh + (size_t)128 * 1024 * 64;
    unsigned short* vt = kh + (size_t)128 * 1024 * 64;
    float*          y  = (float*)d_ws;

    // d_out used as scratch (stream-ordered, fully rewritten later):
    //   first half:  attnb bf16 (16.8 MB @0) + wob bf16 (2.1 MB @+16.8MB); LN overwrites.
    //   second half: xb bf16 (16.8 MB) + wqkvb bf16 (6.3 MB); zeroed after qkv
    //   (scratch dead) for the attn kernel's atomic wout accumulation.
    unsigned short* attnb = (unsigned short*)d_out;
    unsigned short* wob   = (unsigned short*)d_out + (size_t)NROWS * DMODEL;
    unsigned short* xb    = (unsigned short*)out_w;
    unsigned short* wqkvb = xb + (size_t)NROWS * DMODEL;

    cvt_bf16    <<<(NG_X + NG_WQ + NG_WO) / 256, 256, 0, stream>>>(x, wqkv, wo, xb, wqkvb, wob);
    qkv_mfma    <<<dim3(D3 / 128, NROWS / 128), 256, 0, stream>>>(xb, wqkvb, bqkv, qh, kh, vt);
    hipMemsetAsync(out_w, 0, (size_t)BATCH * SEQ * SEQ * sizeof(float), stream);
    attn_mfma   <<<dim3(SEQ / 16, BATCH, 2),    256, 0, stream>>>(qh, kh, vt, td, attnb, out_w);
    outproj_mfma<<<dim3(DMODEL / 128, NROWS / 128), 256, 0, stream>>>(attnb, wob, bo, x, y);
    ln_kernel   <<<NROWS,                       256, 0, stream>>>(y, lnw, lnb, out_ln);
}

// Round 3
// 416.828 us; speedup vs baseline: 1.2266x; 1.2266x over previous
//
#include <hip/hip_runtime.h>
#include <cstddef>

// Problem constants
#define BATCH   8
#define SEQ     1024
#define DMODEL  1024
#define NHEAD   16
#define HDIM    64
#define D3      3072
#define NROWS   (BATCH * SEQ)   // 8192
#define LN_EPS  1e-5f

typedef __attribute__((ext_vector_type(4))) float f32x4;
typedef __attribute__((ext_vector_type(8))) short bf16x8;

// ---------- bf16 helpers ----------
__device__ __forceinline__ float b2f(unsigned short u) {
    union { unsigned int i; float f; } v; v.i = ((unsigned int)u) << 16; return v.f;
}
__device__ __forceinline__ unsigned short f2bu(float f) {  // round-to-nearest-even
    union { float f; unsigned int i; } v; v.f = f;
    unsigned int r = v.i + 0x7fffu + ((v.i >> 16) & 1u);
    return (unsigned short)(r >> 16);
}
// async global->LDS, 16B per lane (wave-uniform base + lane*16)
__device__ __forceinline__ void gl16(const void* g, void* l) {
    __builtin_amdgcn_global_load_lds(
        (const __attribute__((address_space(1))) unsigned int*)g,
        (__attribute__((address_space(3))) unsigned int*)l, 16, 0, 0);
}

// =====================================================================
// K0: fp32 -> bf16 conversion of x, in_proj_w, out_proj_w
// =====================================================================
#define NG_X  1048576   // 8192*1024/8
#define NG_WQ 393216    // 3072*1024/8
#define NG_WO 131072    // 1024*1024/8
__global__ __launch_bounds__(256)
void cvt_bf16(const float* __restrict__ x, const float* __restrict__ wq,
              const float* __restrict__ wo,
              unsigned short* __restrict__ xb, unsigned short* __restrict__ wqb,
              unsigned short* __restrict__ wob) {
    const int gidx = blockIdx.x * 256 + threadIdx.x;
    const float* src; unsigned short* dst; size_t off;
    if (gidx < NG_X)              { src = x;  dst = xb;  off = (size_t)gidx * 8; }
    else if (gidx < NG_X + NG_WQ) { src = wq; dst = wqb; off = (size_t)(gidx - NG_X) * 8; }
    else                          { src = wo; dst = wob; off = (size_t)(gidx - NG_X - NG_WQ) * 8; }
    float4 v0 = *(const float4*)(src + off);
    float4 v1 = *(const float4*)(src + off + 4);
    uint4 pv;
    pv.x = f2bu(v0.x) | ((unsigned int)f2bu(v0.y) << 16);
    pv.y = f2bu(v0.z) | ((unsigned int)f2bu(v0.w) << 16);
    pv.z = f2bu(v1.x) | ((unsigned int)f2bu(v1.y) << 16);
    pv.w = f2bu(v1.z) | ((unsigned int)f2bu(v1.w) << 16);
    *(uint4*)(dst + off) = pv;
}

// =====================================================================
// K1: qkv MFMA GEMM. C[8192,3072] = xb @ wb^T + bias  (bf16 in, bf16 out)
// Q -> qh[(b*16+h)][tok][64], K -> kh[(b*16+h)][key][64]  (per-head slabs)
// V -> vt[(b*16+h)*64+d][key] transposed.
// 128x128 tile, BK=32, 4 waves (2x2), 16x16x32 MFMA, global_load_lds x16B.
// =====================================================================
__global__ __launch_bounds__(256)
void qkv_mfma(const unsigned short* __restrict__ xb,    // [8192][1024]
              const unsigned short* __restrict__ wb,    // [3072][1024]
              const float* __restrict__ bias,           // [3072]
              unsigned short* __restrict__ qh,          // [128][1024][64]
              unsigned short* __restrict__ kh,          // [128][1024][64]
              unsigned short* __restrict__ vt) {        // [128*64][1024]
    __shared__ unsigned short smem[8192];               // As 4096 | Bs 4096 (16 KB)
    unsigned short* As = smem;
    unsigned short* Bs = smem + 4096;

    const int t = threadIdx.x;
    const int w = t >> 6, lane = t & 63;
    const int wm = w >> 1, wn = w & 1;
    const int g = lane >> 4, c = lane & 15;
    const int m0 = blockIdx.y * 128, n0 = blockIdx.x * 128;

    const int srow = t >> 2;            // 0..63
    const int scol = (t & 3) * 8;       // 0,8,16,24
    const unsigned short* ga = xb + (size_t)(m0 + srow) * 1024 + scol;
    const unsigned short* gb = wb + (size_t)(n0 + srow) * 1024 + scol;

    f32x4 acc[4][4];
#pragma unroll
    for (int i = 0; i < 4; ++i)
#pragma unroll
        for (int j = 0; j < 4; ++j) acc[i][j] = (f32x4){0.f, 0.f, 0.f, 0.f};

    for (int k0 = 0; k0 < 1024; k0 += 32) {
        gl16(ga + k0,             As + t * 8);
        gl16(ga + 64 * 1024 + k0, As + 2048 + t * 8);
        gl16(gb + k0,             Bs + t * 8);
        gl16(gb + 64 * 1024 + k0, Bs + 2048 + t * 8);
        __syncthreads();                         // drains vmcnt -> tile visible
        bf16x8 af[4], bf[4];
#pragma unroll
        for (int i = 0; i < 4; ++i)
            af[i] = *(const bf16x8*)(As + (wm * 64 + i * 16 + c) * 32 + g * 8);
#pragma unroll
        for (int j = 0; j < 4; ++j)
            bf[j] = *(const bf16x8*)(Bs + (wn * 64 + j * 16 + c) * 32 + g * 8);
#pragma unroll
        for (int i = 0; i < 4; ++i)
#pragma unroll
            for (int j = 0; j < 4; ++j)
                acc[i][j] = __builtin_amdgcn_mfma_f32_16x16x32_bf16(af[i], bf[j], acc[i][j], 0, 0, 0);
        __syncthreads();                         // protect tile before next overwrite
    }

    float bsv[4];
#pragma unroll
    for (int j = 0; j < 4; ++j) bsv[j] = bias[n0 + wn * 64 + j * 16 + c];

    unsigned short* eslice = smem + w * 2048;    // 4 KB per-wave epilogue slice
    const int b_ = m0 >> 10;                     // batch (tile never straddles)

    if (n0 < 2048) {
        // ---- Q or K: per-head slab [128 slabs][1024 tok][64 d] ----
        const int ncl   = n0 + wn * 64;          // wave's 64-col slice = one head
        unsigned short* dst = (ncl < 1024)
            ? qh + ((size_t)(b_ * 16 + (ncl >> 6)) * 1024) * 64
            : kh + ((size_t)(b_ * 16 + ((ncl - 1024) >> 6)) * 1024) * 64;
#pragma unroll
        for (int half = 0; half < 2; ++half) {
#pragma unroll
            for (int ii = 0; ii < 2; ++ii) {
                const int i = half * 2 + ii;
#pragma unroll
                for (int j = 0; j < 4; ++j)
#pragma unroll
                    for (int r = 0; r < 4; ++r)
                        eslice[(ii * 16 + g * 4 + r) * 64 + j * 16 + c] = f2bu(acc[i][j][r] + bsv[j]);
            }
#pragma unroll
            for (int u = 0; u < 4; ++u) {
                const int mloc = u * 8 + (lane >> 3);       // 0..31
                const int ncol = (lane & 7) * 8;
                bf16x8 row = *(const bf16x8*)(eslice + mloc * 64 + ncol);
                const int tok = (m0 & 1023) + wm * 64 + half * 32 + mloc;
                *(bf16x8*)(dst + (size_t)tok * 64 + ncol) = row;
            }
        }
    } else {
        // ---- V: transposed into vt[(b*16+h)*64+d][key], XOR-swizzled LDS ----
        const int key0  = (m0 & 1023) + wm * 64;
        const int hbase = (n0 + wn * 64 - 2048) >> 6;
#pragma unroll
        for (int half = 0; half < 2; ++half) {
#pragma unroll
            for (int jj = 0; jj < 2; ++jj) {
                const int j = half * 2 + jj;
                const int nloc = jj * 16 + c;               // 0..31
#pragma unroll
                for (int i = 0; i < 4; ++i)
#pragma unroll
                    for (int r = 0; r < 4; ++r) {
                        const int mloc  = i * 16 + g * 4 + r;
                        const int mphys = mloc ^ ((nloc & 7) << 3);
                        eslice[nloc * 64 + mphys] = f2bu(acc[i][j][r] + bsv[j]);
                    }
            }
#pragma unroll
            for (int u = 0; u < 4; ++u) {
                const int nloc  = u * 8 + (lane >> 3);      // 0..31
                const int mb    = lane & 7;
                const int mphys = (mb ^ (nloc & 7)) * 8;
                bf16x8 row = *(const bf16x8*)(eslice + nloc * 64 + mphys);
                const int d = half * 32 + nloc;
                *(bf16x8*)(vt + ((size_t)((b_ * 16 + hbase) * 64 + d)) * 1024 + key0 + mb * 8) = row;
            }
        }
    }
}

// =====================================================================
// K2: MFMA attention. Block = (qtile of 32 rows, batch, head-group of 8).
// 256 threads, 4 waves splitting the key dimension (256 keys each).
// Theory: per-CU L1 miss-fill (gather line) throughput is the limit.
// Amortize K/V gathers over 2x output: two 16-row MFMA q-tiles per block
// share every kb/vb fragment load -> line fills per output halve.
//  - wsum [2][16][4] = 128 regs/thread; ~2 waves/SIMD expected.
//  - P_s[32][1032] = 66KB -> 2 blocks/CU.
//  - PV interleaves the two accO chains (2x MFMA ILP).
//  - exp2 via __builtin_amdgcn_exp2f with pre-folded log2e constants.
// =====================================================================
__global__ __launch_bounds__(256, 2)
void attn_mfma(const unsigned short* __restrict__ qh,   // [128][1024][64]
               const unsigned short* __restrict__ kh,   // [128][1024][64]
               const unsigned short* __restrict__ vt,   // [128][64][1024]
               const float* __restrict__ tdp,
               unsigned short* __restrict__ attnb,       // [8192][1024] bf16
               float* __restrict__ wout) {               // [8192][1024] pre-zeroed
    const int qt = blockIdx.x;      // 0..31
    const int b  = blockIdx.y;      // 0..7
    const int hg = blockIdx.z;      // 0..1 (head group)
    const int t  = threadIdx.x;
    const int w  = t >> 6;          // wave 0..3
    const int lane = t & 63;
    const int g  = lane >> 4;       // quad group 0..3
    const int c  = lane & 15;

    const int q0 = qt * 32;
    const float td2 = -fabsf(tdp[0]) * 1.44269504f;   // decay in log2 domain
    const float sc2 = 0.125f * 1.44269504f;           // qk scale in log2 domain

    __shared__ unsigned short P_s[32][1032];   // unnormalized e (bf16), 2 q-tiles
    __shared__ float rs_s[4][32];              // per-wave row sums

    float wsum[2][16][4];                       // head-mean accumulator
#pragma unroll
    for (int i = 0; i < 2; ++i)
#pragma unroll
        for (int tt = 0; tt < 16; ++tt)
#pragma unroll
            for (int r = 0; r < 4; ++r) wsum[i][tt][r] = 0.f;

    const int key_base = w * 256;               // wave's key range in QK^T
    const float kf0 = (float)(key_base + c);

    for (int hi = 0; hi < 8; ++hi) {
        const int h = hg * 8 + hi;
        const unsigned short* qslab = qh + (size_t)(b * 16 + h) * 1024 * 64;
        const unsigned short* kslab = kh + (size_t)(b * 16 + h) * 1024 * 64;

        // A-frags: 2 q-tiles x 2 k-halves
        bf16x8 qa[2][2];
#pragma unroll
        for (int i = 0; i < 2; ++i) {
            const unsigned short* qp = qslab + (size_t)(q0 + i * 16 + c) * 64 + g * 8;
            qa[i][0] = *(const bf16x8*)(qp);
            qa[i][1] = *(const bf16x8*)(qp + 32);
        }

        // ---- chunked QK^T: each kb pair feeds BOTH q-tiles ----
        float rsum[2][4] = {{0.f,0.f,0.f,0.f},{0.f,0.f,0.f,0.f}};
#pragma unroll 2
        for (int tt = 0; tt < 16; ++tt) {
            const int key = key_base + tt * 16 + c;      // B-frag n = c
            const unsigned short* kp = kslab + (size_t)key * 64 + g * 8;
            bf16x8 kb0 = *(const bf16x8*)(kp);
            bf16x8 kb1 = *(const bf16x8*)(kp + 32);
            f32x4 z0 = {0.f, 0.f, 0.f, 0.f};
            f32x4 z1 = {0.f, 0.f, 0.f, 0.f};
            z0 = __builtin_amdgcn_mfma_f32_16x16x32_bf16(qa[0][0], kb0, z0, 0, 0, 0);
            z1 = __builtin_amdgcn_mfma_f32_16x16x32_bf16(qa[1][0], kb0, z1, 0, 0, 0);
            z0 = __builtin_amdgcn_mfma_f32_16x16x32_bf16(qa[0][1], kb1, z0, 0, 0, 0);
            z1 = __builtin_amdgcn_mfma_f32_16x16x32_bf16(qa[1][1], kb1, z1, 0, 0, 0);
            const float kf = kf0 + (float)(tt * 16);
#pragma unroll
            for (int r = 0; r < 4; ++r) {
                const float qf0 = (float)(q0 + g * 4 + r);
                const float e0 = __builtin_amdgcn_exp2f(z0[r] * sc2 + td2 * fabsf(kf - qf0));
                rsum[0][r] += e0;
                P_s[g * 4 + r][key_base + tt * 16 + c] = f2bu(e0);
                const float qf1 = qf0 + 16.0f;
                const float e1 = __builtin_amdgcn_exp2f(z1[r] * sc2 + td2 * fabsf(kf - qf1));
                rsum[1][r] += e1;
                P_s[16 + g * 4 + r][key_base + tt * 16 + c] = f2bu(e1);
            }
        }
#pragma unroll
        for (int i = 0; i < 2; ++i)
#pragma unroll
            for (int r = 0; r < 4; ++r) {
                rsum[i][r] += __shfl_xor(rsum[i][r], 1, 64);
                rsum[i][r] += __shfl_xor(rsum[i][r], 2, 64);
                rsum[i][r] += __shfl_xor(rsum[i][r], 4, 64);
                rsum[i][r] += __shfl_xor(rsum[i][r], 8, 64);
            }
        if (c == 0) {
#pragma unroll
            for (int i = 0; i < 2; ++i)
#pragma unroll
                for (int r = 0; r < 4; ++r) rs_s[w][i * 16 + g * 4 + r] = rsum[i][r];
        }
        __syncthreads();                        // publishes P_s AND rs_s

        float invl[2][4];
#pragma unroll
        for (int i = 0; i < 2; ++i)
#pragma unroll
            for (int r = 0; r < 4; ++r) {
                const int row = i * 16 + g * 4 + r;
                invl[i][r] = 1.0f / (rs_s[0][row] + rs_s[1][row] + rs_s[2][row] + rs_s[3][row]);
            }

        // ---- PV: each vb load feeds BOTH q-tiles; 2 independent chains ----
        f32x4 accO0 = {0.f, 0.f, 0.f, 0.f};
        f32x4 accO1 = {0.f, 0.f, 0.f, 0.f};
        const unsigned short* vhp = vt + (size_t)((b * 16 + h) * 64 + w * 16 + c) * 1024;
#pragma unroll 4
        for (int ks = 0; ks < 32; ++ks) {
            bf16x8 pa0 = *(const bf16x8*)(&P_s[c][ks * 32 + g * 8]);
            bf16x8 pa1 = *(const bf16x8*)(&P_s[16 + c][ks * 32 + g * 8]);
            bf16x8 vb  = *(const bf16x8*)(vhp + ks * 32 + g * 8);
            accO0 = __builtin_amdgcn_mfma_f32_16x16x32_bf16(pa0, vb, accO0, 0, 0, 0);
            accO1 = __builtin_amdgcn_mfma_f32_16x16x32_bf16(pa1, vb, accO1, 0, 0, 0);
        }
        {
            unsigned short* op0 = attnb + (size_t)(b * 1024 + q0) * 1024 + h * 64 + w * 16 + c;
            unsigned short* op1 = op0 + (size_t)16 * 1024;
#pragma unroll
            for (int r = 0; r < 4; ++r) {
                op0[(size_t)(g * 4 + r) * 1024] = f2bu(accO0[r] * invl[0][r]);
                op1[(size_t)(g * 4 + r) * 1024] = f2bu(accO1[r] * invl[1][r]);
            }
        }

        // ---- wsum: re-read own e-values (bf16) and normalize ----
#pragma unroll
        for (int tt = 0; tt < 16; ++tt) {
#pragma unroll
            for (int r = 0; r < 4; ++r) {
                wsum[0][tt][r] += b2f(P_s[g * 4 + r][key_base + tt * 16 + c]) * invl[0][r];
                wsum[1][tt][r] += b2f(P_s[16 + g * 4 + r][key_base + tt * 16 + c]) * invl[1][r];
            }
        }
        __syncthreads();                        // P_s reusable next head
    }

    // head-group partial -> atomic accumulate (2 contenders per element)
#pragma unroll
    for (int i = 0; i < 2; ++i)
#pragma unroll
        for (int tt = 0; tt < 16; ++tt)
#pragma unroll
            for (int r = 0; r < 4; ++r) {
                atomicAdd(&wout[(size_t)(b * 1024 + q0 + i * 16 + g * 4 + r) * 1024
                                 + key_base + tt * 16 + c],
                          wsum[i][tt][r] * (1.0f / NHEAD));
            }
}

// =====================================================================
// K3: outproj MFMA. y = attnb @ wob^T + bias + x   (bf16 in, fp32 out)
// =====================================================================
__global__ __launch_bounds__(256)
void outproj_mfma(const unsigned short* __restrict__ ab,   // [8192][1024]
                  const unsigned short* __restrict__ wob,  // [1024][1024]
                  const float* __restrict__ bias,
                  const float* __restrict__ X,
                  float* __restrict__ Y) {
    __shared__ unsigned short smem[8192];
    unsigned short* As = smem;
    unsigned short* Bs = smem + 4096;

    const int t = threadIdx.x;
    const int w = t >> 6, lane = t & 63;
    const int wm = w >> 1, wn = w & 1;
    const int g = lane >> 4, c = lane & 15;
    const int m0 = blockIdx.y * 128, n0 = blockIdx.x * 128;

    const int srow = t >> 2;
    const int scol = (t & 3) * 8;
    const unsigned short* ga = ab  + (size_t)(m0 + srow) * 1024 + scol;
    const unsigned short* gb = wob + (size_t)(n0 + srow) * 1024 + scol;

    f32x4 acc[4][4];
#pragma unroll
    for (int i = 0; i < 4; ++i)
#pragma unroll
        for (int j = 0; j < 4; ++j) acc[i][j] = (f32x4){0.f, 0.f, 0.f, 0.f};

    for (int k0 = 0; k0 < 1024; k0 += 32) {
        gl16(ga + k0,             As + t * 8);
        gl16(ga + 64 * 1024 + k0, As + 2048 + t * 8);
        gl16(gb + k0,             Bs + t * 8);
        gl16(gb + 64 * 1024 + k0, Bs + 2048 + t * 8);
        __syncthreads();
        bf16x8 af[4], bf[4];
#pragma unroll
        for (int i = 0; i < 4; ++i)
            af[i] = *(const bf16x8*)(As + (wm * 64 + i * 16 + c) * 32 + g * 8);
#pragma unroll
        for (int j = 0; j < 4; ++j)
            bf[j] = *(const bf16x8*)(Bs + (wn * 64 + j * 16 + c) * 32 + g * 8);
#pragma unroll
        for (int i = 0; i < 4; ++i)
#pragma unroll
            for (int j = 0; j < 4; ++j)
                acc[i][j] = __builtin_amdgcn_mfma_f32_16x16x32_bf16(af[i], bf[j], acc[i][j], 0, 0, 0);
        __syncthreads();
    }

    float bsv[4];
#pragma unroll
    for (int j = 0; j < 4; ++j) bsv[j] = bias[n0 + wn * 64 + j * 16 + c];

#pragma unroll
    for (int i = 0; i < 4; ++i) {
#pragma unroll
        for (int r = 0; r < 4; ++r) {
            const int m = m0 + wm * 64 + i * 16 + g * 4 + r;
#pragma unroll
            for (int j = 0; j < 4; ++j) {
                const int n = n0 + wn * 64 + j * 16 + c;
                Y[(size_t)m * 1024 + n] = acc[i][j][r] + bsv[j] + X[(size_t)m * 1024 + n];
            }
        }
    }
}

// =====================================================================
// K4: LayerNorm per row -> final out
// =====================================================================
__global__ __launch_bounds__(256)
void ln_kernel(const float* __restrict__ Y, const float* __restrict__ lnw,
               const float* __restrict__ lnb, float* __restrict__ out) {
    const int row = blockIdx.x, t = threadIdx.x;
    __shared__ float rs[256], rq[256];
    const float4 v = ((const float4*)(Y + (size_t)row * DMODEL))[t];
    rs[t] = v.x + v.y + v.z + v.w;
    rq[t] = v.x * v.x + v.y * v.y + v.z * v.z + v.w * v.w;
    __syncthreads();
    for (int off = 128; off > 0; off >>= 1) {
        if (t < off) { rs[t] += rs[t + off]; rq[t] += rq[t + off]; }
        __syncthreads();
    }
    const float mu   = rs[0] * (1.0f / DMODEL);
    const float var  = rq[0] * (1.0f / DMODEL) - mu * mu;
    const float rstd = rsqrtf(var + LN_EPS);
    const float4 w  = ((const float4*)lnw)[t];
    const float4 bb = ((const float4*)lnb)[t];
    float4 o;
    o.x = (v.x - mu) * rstd * w.x + bb.x;
    o.y = (v.y - mu) * rstd * w.y + bb.y;
    o.z = (v.z - mu) * rstd * w.z + bb.z;
    o.w = (v.w - mu) * rstd * w.w + bb.w;
    ((float4*)(out + (size_t)row * DMODEL))[t] = o;
}

// =====================================================================
extern "C" void kernel_launch(void* const* d_in, const int* in_sizes, int n_in,
                              void* d_out, int out_size, void* d_ws, size_t ws_size,
                              hipStream_t stream) {
    (void)in_sizes; (void)n_in; (void)out_size; (void)ws_size;
    const float* x    = (const float*)d_in[0];
    const float* td   = (const float*)d_in[1];
    const float* wqkv = (const float*)d_in[2];
    const float* bqkv = (const float*)d_in[3];
    const float* wo   = (const float*)d_in[4];
    const float* bo   = (const float*)d_in[5];
    const float* lnw  = (const float*)d_in[6];
    const float* lnb  = (const float*)d_in[7];

    float* out_ln = (float*)d_out;                         // final out [8192,1024]
    float* out_w  = (float*)d_out + (size_t)NROWS * SEQ;   // mean weights [8,1024,1024]

    // ws (peak 48 MiB):
    //   qh bf16 [128][1024][64] @0        (16 MiB)
    //   kh bf16 [128][1024][64] @+16 MiB  (16 MiB)
    //   vt bf16 [128*64][1024]  @+32 MiB  (16 MiB)
    //   y  fp32 [8192][1024] reuses offset 0 after attn (qh/kh dead).
    unsigned short* qh = (unsigned short*)d_ws;
    unsigned short* kh = qh + (size_t)128 * 1024 * 64;
    unsigned short* vt = kh + (size_t)128 * 1024 * 64;
    float*          y  = (float*)d_ws;

    // d_out used as scratch (stream-ordered, fully rewritten later):
    //   first half:  attnb bf16 (16.8 MB @0) + wob bf16 (2.1 MB @+16.8MB); LN overwrites.
    //   second half: xb bf16 (16.8 MB) + wqkvb bf16 (6.3 MB); zeroed after qkv
    //   (scratch dead) for the attn kernel's atomic wout accumulation.
    unsigned short* attnb = (unsigned short*)d_out;
    unsigned short* wob   = (unsigned short*)d_out + (size_t)NROWS * DMODEL;
    unsigned short* xb    = (unsigned short*)out_w;
    unsigned short* wqkvb = xb + (size_t)NROWS * DMODEL;

    cvt_bf16    <<<(NG_X + NG_WQ + NG_WO) / 256, 256, 0, stream>>>(x, wqkv, wo, xb, wqkvb, wob);
    qkv_mfma    <<<dim3(D3 / 128, NROWS / 128), 256, 0, stream>>>(xb, wqkvb, bqkv, qh, kh, vt);
    (void)hipMemsetAsync(out_w, 0, (size_t)BATCH * SEQ * SEQ * sizeof(float), stream);
    attn_mfma   <<<dim3(SEQ / 32, BATCH, 2),    256, 0, stream>>>(qh, kh, vt, td, attnb, out_w);
    outproj_mfma<<<dim3(DMODEL / 128, NROWS / 128), 256, 0, stream>>>(attnb, wob, bo, x, y);
    ln_kernel   <<<NROWS,                       256, 0, stream>>>(y, lnw, lnb, out_ln);
}